// Round 2
// baseline (604.543 us; speedup 1.0000x reference)
//
#include <hip/hip_runtime.h>

#define B_ 16
#define P_ 12
#define N_ 2048
#define H_ 64
#define E_ 16384
#define NH_ (N_*H_)            // 131072
#define NG_ (B_*P_)            // 192

// ---------------- Kernel A: partial sums of x per (b,p) plane ----------------
__global__ __launch_bounds__(256) void k_stats_x(const float* __restrict__ x,
                                                 float* __restrict__ partials /*[NG_*8][2]*/) {
    int g   = blockIdx.x >> 3;
    int seg = blockIdx.x & 7;
    const float4* xg = (const float4*)(x + (size_t)g * NH_);
    float s = 0.f, q = 0.f;
    int base = seg * 4096;                 // float4 index
    #pragma unroll
    for (int i = 0; i < 16; ++i) {
        float4 v = xg[base + i*256 + threadIdx.x];
        s += v.x + v.y + v.z + v.w;
        q += v.x*v.x + v.y*v.y + v.z*v.z + v.w*v.w;
    }
    __shared__ float ls[4], lq[4];
    for (int off = 32; off; off >>= 1) { s += __shfl_down(s, off); q += __shfl_down(q, off); }
    int wid = threadIdx.x >> 6, lane = threadIdx.x & 63;
    if (!lane) { ls[wid] = s; lq[wid] = q; }
    __syncthreads();
    if (!threadIdx.x) {
        partials[blockIdx.x*2]   = ls[0]+ls[1]+ls[2]+ls[3];
        partials[blockIdx.x*2+1] = lq[0]+lq[1]+lq[2]+lq[3];
    }
}

// ---------------- finalize: partials -> mean/rstd per group ----------------
__global__ __launch_bounds__(64) void k_finalize(const float* __restrict__ partials, int cnt,
                                                 float* __restrict__ mean, float* __restrict__ rstd) {
    int g = blockIdx.x, lane = threadIdx.x;
    float s = (lane < cnt) ? partials[(g*cnt+lane)*2]   : 0.f;
    float q = (lane < cnt) ? partials[(g*cnt+lane)*2+1] : 0.f;
    for (int off = 8; off; off >>= 1) { s += __shfl_down(s, off); q += __shfl_down(q, off); }
    if (!lane) {
        float m = s * (1.0f/NH_);
        float v = q * (1.0f/NH_) - m*m;
        mean[g] = m;
        rstd[g] = rsqrtf(v + 1e-5f);
    }
}

// ---------------- CSR build (single block) with int32/int64 detection ----------------
__global__ __launch_bounds__(1024) void k_build_csr(const int* __restrict__ ew,
                                                    int* __restrict__ rowPtr,
                                                    int* __restrict__ csrSrc,
                                                    float* __restrict__ csrW) {
    __shared__ int   sDeg[N_];
    __shared__ int   sA[N_];
    __shared__ int   sB[N_];
    __shared__ float sDinv[N_];
    __shared__ int   sFlag;
    int tid = threadIdx.x;
    if (!tid) sFlag = 1;
    for (int i = tid; i < N_; i += 1024) sDeg[i] = 0;
    __syncthreads();
    // int64 edge_index => int32 view has zero high words at odd indices
    if (tid < 256) { if (ew[2*tid+1] != 0) atomicAnd(&sFlag, 0); }
    __syncthreads();
    int is64 = sFlag;
    for (int e = tid; e < E_; e += 1024) {
        int dst = is64 ? ew[2*(E_+e)] : ew[E_+e];
        atomicAdd(&sDeg[dst], 1);
    }
    __syncthreads();
    for (int i = tid; i < N_; i += 1024) {
        int d = sDeg[i];
        sDinv[i] = d > 0 ? rsqrtf((float)d) : 0.f;
        sA[i] = d;
    }
    __syncthreads();
    // inclusive Kogge-Stone scan over sA (double-buffered)
    int* in = sA; int* out = sB;
    for (int st = 1; st < N_; st <<= 1) {
        for (int i = tid; i < N_; i += 1024) {
            int v = in[i];
            if (i >= st) v += in[i-st];
            out[i] = v;
        }
        __syncthreads();
        int* t = in; in = out; out = t;
    }
    // exclusive offsets; reuse 'out' as fill cursor
    for (int i = tid; i < N_; i += 1024) {
        int excl = in[i] - sDeg[i];
        rowPtr[i] = excl;
        out[i] = excl;
    }
    if (!tid) rowPtr[N_] = E_;
    __syncthreads();
    for (int e = tid; e < E_; e += 1024) {
        int src = is64 ? ew[2*e]       : ew[e];
        int dst = is64 ? ew[2*(E_+e)]  : ew[E_+e];
        int pos = atomicAdd(&out[dst], 1);
        csrSrc[pos] = src;
        csrW[pos] = sDinv[src] * sDinv[dst];
    }
}

// ---------------- gather: LN1-on-the-fly + LightGCN conv + LN2 partial stats ----------------
__global__ __launch_bounds__(256) void k_gather(const float* __restrict__ x,
                                                const float* __restrict__ gw,
                                                const float* __restrict__ gb,
                                                const float* __restrict__ mean1,
                                                const float* __restrict__ rstd1,
                                                const int* __restrict__ rowPtr,
                                                const int* __restrict__ csrSrc,
                                                const float* __restrict__ csrW,
                                                float* __restrict__ h2,        // staged in d_out
                                                float* __restrict__ partials /*[NG_*16][2]*/) {
    int g   = blockIdx.x >> 4;
    int blk = blockIdx.x & 15;
    int wid = threadIdx.x >> 6, lane = threadIdx.x & 63;
    const float* xg = x + (size_t)g * NH_;
    float mean = mean1[g], rstd = rstd1[g];
    float s = 0.f, q = 0.f;
    int n0 = blk*128 + wid*32;
    for (int i = 0; i < 32; ++i) {
        int n = n0 + i;
        int r0 = rowPtr[n], r1 = rowPtr[n+1];
        float acc = 0.f;
        for (int j = r0; j < r1; ++j) {
            int   src = csrSrc[j];
            float w   = csrW[j];
            float xv  = xg[src*H_ + lane];
            float h1  = (xv - mean)*rstd*gw[src*H_ + lane] + gb[src*H_ + lane];
            acc += w*h1;
        }
        h2[(size_t)g*NH_ + n*H_ + lane] = acc;
        s += acc; q += acc*acc;
    }
    __shared__ float ls[4], lq[4];
    for (int off = 32; off; off >>= 1) { s += __shfl_down(s, off); q += __shfl_down(q, off); }
    if (!lane) { ls[wid] = s; lq[wid] = q; }
    __syncthreads();
    if (!threadIdx.x) {
        partials[blockIdx.x*2]   = ls[0]+ls[1]+ls[2]+ls[3];
        partials[blockIdx.x*2+1] = lq[0]+lq[1]+lq[2]+lq[3];
    }
}

// ---------------- mix: LN2 + 1x1 conv over P, in place on d_out ----------------
__global__ __launch_bounds__(256) void k_mix(float* __restrict__ h2,   // in/out = d_out
                                             const float* __restrict__ tw,
                                             const float* __restrict__ tb,
                                             const float* __restrict__ cw,
                                             const float* __restrict__ cb,
                                             const float* __restrict__ mean2,
                                             const float* __restrict__ rstd2) {
    __shared__ float scw[P_*P_], scb[P_], sm[P_], sr[P_], srow[P_];
    int b     = blockIdx.x >> 7;
    int chunk = blockIdx.x & 127;
    int tid   = threadIdx.x;
    if (tid < P_*P_) scw[tid] = cw[tid];
    if (tid < P_) {
        scb[tid] = cb[tid];
        sm[tid]  = mean2[b*P_ + tid];
        sr[tid]  = rstd2[b*P_ + tid];
    }
    __syncthreads();
    if (tid < P_) {
        float rs = 0.f;
        #pragma unroll
        for (int p = 0; p < P_; ++p) rs += scw[tid*P_ + p];
        srow[tid] = rs;
    }
    __syncthreads();
    int elem4 = chunk*256 + tid;           // 0..32767 = NH_/4
    size_t base = (size_t)b * P_ * NH_;
    float4 v[P_];
    #pragma unroll
    for (int p = 0; p < P_; ++p) {
        float4 t = *(const float4*)(h2 + base + (size_t)p*NH_ + (size_t)elem4*4);
        float m = sm[p], r = sr[p];
        v[p].x = (t.x-m)*r; v[p].y = (t.y-m)*r; v[p].z = (t.z-m)*r; v[p].w = (t.w-m)*r;
    }
    float4 tw4 = *(const float4*)(tw + (size_t)elem4*4);
    float4 tb4 = *(const float4*)(tb + (size_t)elem4*4);
    #pragma unroll
    for (int q = 0; q < P_; ++q) {
        float4 a = {0.f,0.f,0.f,0.f};
        #pragma unroll
        for (int p = 0; p < P_; ++p) {
            float c = scw[q*P_ + p];
            a.x += c*v[p].x; a.y += c*v[p].y; a.z += c*v[p].z; a.w += c*v[p].w;
        }
        float rb = srow[q], cbq = scb[q];
        float4 o;
        o.x = tw4.x*a.x + tb4.x*rb + cbq;
        o.y = tw4.y*a.y + tb4.y*rb + cbq;
        o.z = tw4.z*a.z + tb4.z*rb + cbq;
        o.w = tw4.w*a.w + tb4.w*rb + cbq;
        *(float4*)(h2 + base + (size_t)q*NH_ + (size_t)elem4*4) = o;
    }
}

extern "C" void kernel_launch(void* const* d_in, const int* in_sizes, int n_in,
                              void* d_out, int out_size, void* d_ws, size_t ws_size,
                              hipStream_t stream) {
    const float* x  = (const float*)d_in[0];
    const int*   ew = (const int*)d_in[1];
    const float* gw = (const float*)d_in[2];
    const float* gb = (const float*)d_in[3];
    const float* tw = (const float*)d_in[4];
    const float* tb = (const float*)d_in[5];
    const float* cw = (const float*)d_in[6];
    const float* cb = (const float*)d_in[7];
    float* out = (float*)d_out;
    float* wf  = (float*)d_ws;

    // ws layout (floats): mean1[192] rstd1[192] mean2[192] rstd2[192]
    // pA[192*8*2] @768, pC[192*16*2] @3840, rowPtr(int)[2049] @10240,
    // csrSrc(int)[16384] @12544, csrW[16384] @29184   (total ~183 KB)
    float* mean1  = wf + 0;
    float* rstd1  = wf + 192;
    float* mean2  = wf + 384;
    float* rstd2  = wf + 576;
    float* pA     = wf + 768;
    float* pC     = wf + 3840;
    int*   rowPtr = (int*)(wf + 10240);
    int*   csrSrc = (int*)(wf + 12544);
    float* csrW   = wf + 29184;

    k_stats_x<<<NG_*8, 256, 0, stream>>>(x, pA);
    k_finalize<<<NG_, 64, 0, stream>>>(pA, 8, mean1, rstd1);
    k_build_csr<<<1, 1024, 0, stream>>>(ew, rowPtr, csrSrc, csrW);
    k_gather<<<NG_*16, 256, 0, stream>>>(x, gw, gb, mean1, rstd1,
                                         rowPtr, csrSrc, csrW, out, pC);
    k_finalize<<<NG_, 64, 0, stream>>>(pC, 16, mean2, rstd2);
    k_mix<<<B_*128, 256, 0, stream>>>(out, tw, tb, cw, cb, mean2, rstd2);
}

// Round 3
// 367.697 us; speedup vs baseline: 1.6441x; 1.6441x over previous
//
#include <hip/hip_runtime.h>

#define B_ 16
#define P_ 12
#define N_ 2048
#define H_ 64
#define E_ 16384
#define NH_ (N_*H_)            // 131072
#define NG_ (B_*P_)            // 192

// ---------------- Kernel A: partial sums of x per (b,p) plane ----------------
__global__ __launch_bounds__(256) void k_stats_x(const float* __restrict__ x,
                                                 float* __restrict__ partials /*[NG_*8][2]*/) {
    int g   = blockIdx.x >> 3;
    int seg = blockIdx.x & 7;
    const float4* xg = (const float4*)(x + (size_t)g * NH_);
    float s = 0.f, q = 0.f;
    int base = seg * 4096;                 // float4 index
    #pragma unroll
    for (int i = 0; i < 16; ++i) {
        float4 v = xg[base + i*256 + threadIdx.x];
        s += v.x + v.y + v.z + v.w;
        q += v.x*v.x + v.y*v.y + v.z*v.z + v.w*v.w;
    }
    __shared__ float ls[4], lq[4];
    for (int off = 32; off; off >>= 1) { s += __shfl_down(s, off); q += __shfl_down(q, off); }
    int wid = threadIdx.x >> 6, lane = threadIdx.x & 63;
    if (!lane) { ls[wid] = s; lq[wid] = q; }
    __syncthreads();
    if (!threadIdx.x) {
        partials[blockIdx.x*2]   = ls[0]+ls[1]+ls[2]+ls[3];
        partials[blockIdx.x*2+1] = lq[0]+lq[1]+lq[2]+lq[3];
    }
}

// ---------------- finalize: partials -> mean/rstd per group (cnt <= 64) ----------------
__global__ __launch_bounds__(64) void k_finalize(const float* __restrict__ partials, int cnt,
                                                 float* __restrict__ mean, float* __restrict__ rstd) {
    int g = blockIdx.x, lane = threadIdx.x;
    float s = (lane < cnt) ? partials[(g*cnt+lane)*2]   : 0.f;
    float q = (lane < cnt) ? partials[(g*cnt+lane)*2+1] : 0.f;
    for (int off = 32; off; off >>= 1) { s += __shfl_down(s, off); q += __shfl_down(q, off); }
    if (!lane) {
        float m = s * (1.0f/NH_);
        float v = q * (1.0f/NH_) - m*m;
        mean[g] = m;
        rstd[g] = rsqrtf(v + 1e-5f);
    }
}

// ---------------- CSR build (single block) with int32/int64 detection ----------------
__global__ __launch_bounds__(1024) void k_build_csr(const int* __restrict__ ew,
                                                    int* __restrict__ rowPtr,
                                                    int* __restrict__ csrSrc,
                                                    float* __restrict__ csrW) {
    __shared__ int   sDeg[N_];
    __shared__ int   sA[N_];
    __shared__ int   sB[N_];
    __shared__ float sDinv[N_];
    __shared__ int   sFlag;
    int tid = threadIdx.x;
    if (!tid) sFlag = 1;
    for (int i = tid; i < N_; i += 1024) sDeg[i] = 0;
    __syncthreads();
    // int64 edge_index => int32 view has zero high words at odd indices
    if (tid < 256) { if (ew[2*tid+1] != 0) atomicAnd(&sFlag, 0); }
    __syncthreads();
    int is64 = sFlag;
    for (int e = tid; e < E_; e += 1024) {
        int dst = is64 ? ew[2*(E_+e)] : ew[E_+e];
        atomicAdd(&sDeg[dst], 1);
    }
    __syncthreads();
    for (int i = tid; i < N_; i += 1024) {
        int d = sDeg[i];
        sDinv[i] = d > 0 ? rsqrtf((float)d) : 0.f;
        sA[i] = d;
    }
    __syncthreads();
    // inclusive Kogge-Stone scan over sA (double-buffered)
    int* in = sA; int* out = sB;
    for (int st = 1; st < N_; st <<= 1) {
        for (int i = tid; i < N_; i += 1024) {
            int v = in[i];
            if (i >= st) v += in[i-st];
            out[i] = v;
        }
        __syncthreads();
        int* t = in; in = out; out = t;
    }
    // exclusive offsets; reuse 'out' as fill cursor
    for (int i = tid; i < N_; i += 1024) {
        int excl = in[i] - sDeg[i];
        rowPtr[i] = excl;
        out[i] = excl;
    }
    if (!tid) rowPtr[N_] = E_;
    __syncthreads();
    for (int e = tid; e < E_; e += 1024) {
        int src = is64 ? ew[2*e]       : ew[e];
        int dst = is64 ? ew[2*(E_+e)]  : ew[E_+e];
        int pos = atomicAdd(&out[dst], 1);
        csrSrc[pos] = src;
        csrW[pos] = sDinv[src] * sDinv[dst];
    }
}

// ---------------- gather v2: per-wave node, all 12 p-planes of one b at once ----
// h2[b,p,n,h] = rstd*acc_p - mean*rstd*Bn + An
//   acc_p = sum_j w_j*gw_j*x[b,p,src_j,h];  Bn = sum_j w_j*gw_j;  An = sum_j w_j*gb_j
__global__ __launch_bounds__(256) void k_gather(const float* __restrict__ x,
                                                const float* __restrict__ gw,
                                                const float* __restrict__ gb,
                                                const float* __restrict__ mean1,
                                                const float* __restrict__ rstd1,
                                                const int* __restrict__ rowPtr,
                                                const int* __restrict__ csrSrc,
                                                const float* __restrict__ csrW,
                                                float* __restrict__ h2,        // staged in d_out
                                                float* __restrict__ partials /*[192][64][2]*/) {
    int b     = blockIdx.x & 15;           // XCD = blockIdx%8 = b%8 -> b pinned per XCD
    int chunk = blockIdx.x >> 4;           // 0..63, 32 nodes each
    int wid = threadIdx.x >> 6, lane = threadIdx.x & 63;
    __shared__ float s_rs[P_], s_mrs[P_];
    __shared__ float red[4][P_][2];
    if (threadIdx.x < P_) {
        float m = mean1[b*P_ + threadIdx.x], r = rstd1[b*P_ + threadIdx.x];
        s_rs[threadIdx.x] = r; s_mrs[threadIdx.x] = m*r;
    }
    __syncthreads();
    const float* xb = x + (size_t)b * P_ * NH_;
    float sp[P_], qp[P_];
    #pragma unroll
    for (int p = 0; p < P_; ++p) { sp[p] = 0.f; qp[p] = 0.f; }
    for (int i = 0; i < 8; ++i) {
        int n  = chunk*32 + wid*8 + i;
        int r0 = rowPtr[n], r1 = rowPtr[n+1];
        float acc[P_];
        #pragma unroll
        for (int p = 0; p < P_; ++p) acc[p] = 0.f;
        float An = 0.f, Bn = 0.f;
        for (int j = r0; j < r1; ++j) {
            int   src = csrSrc[j];
            float w   = csrW[j];
            int   ro  = src*H_ + lane;
            float t   = w * gw[ro];
            Bn += t;
            An += w * gb[ro];
            #pragma unroll
            for (int p = 0; p < P_; ++p)
                acc[p] += t * xb[(size_t)p*NH_ + ro];
        }
        size_t ob = (size_t)b*P_*NH_ + (size_t)n*H_ + lane;
        #pragma unroll
        for (int p = 0; p < P_; ++p) {
            float val = s_rs[p]*acc[p] - s_mrs[p]*Bn + An;
            h2[ob + (size_t)p*NH_] = val;
            sp[p] += val; qp[p] += val*val;
        }
    }
    #pragma unroll
    for (int p = 0; p < P_; ++p) {
        float s = sp[p], q = qp[p];
        for (int off = 32; off; off >>= 1) { s += __shfl_down(s, off); q += __shfl_down(q, off); }
        if (!lane) { red[wid][p][0] = s; red[wid][p][1] = q; }
    }
    __syncthreads();
    if (threadIdx.x < P_*2) {
        int p = threadIdx.x >> 1, c = threadIdx.x & 1;
        float v = red[0][p][c] + red[1][p][c] + red[2][p][c] + red[3][p][c];
        partials[(((b*P_ + p) << 6) + chunk)*2 + c] = v;
    }
}

// ---------------- mix: LN2 + 1x1 conv over P, in place on d_out ----------------
__global__ __launch_bounds__(256) void k_mix(float* __restrict__ h2,   // in/out = d_out
                                             const float* __restrict__ tw,
                                             const float* __restrict__ tb,
                                             const float* __restrict__ cw,
                                             const float* __restrict__ cb,
                                             const float* __restrict__ mean2,
                                             const float* __restrict__ rstd2) {
    __shared__ float scw[P_*P_], scb[P_], sm[P_], sr[P_], srow[P_];
    int b     = blockIdx.x >> 7;
    int chunk = blockIdx.x & 127;
    int tid   = threadIdx.x;
    if (tid < P_*P_) scw[tid] = cw[tid];
    if (tid < P_) {
        scb[tid] = cb[tid];
        sm[tid]  = mean2[b*P_ + tid];
        sr[tid]  = rstd2[b*P_ + tid];
    }
    __syncthreads();
    if (tid < P_) {
        float rs = 0.f;
        #pragma unroll
        for (int p = 0; p < P_; ++p) rs += scw[tid*P_ + p];
        srow[tid] = rs;
    }
    __syncthreads();
    int elem4 = chunk*256 + tid;           // 0..32767 = NH_/4
    size_t base = (size_t)b * P_ * NH_;
    float4 v[P_];
    #pragma unroll
    for (int p = 0; p < P_; ++p) {
        float4 t = *(const float4*)(h2 + base + (size_t)p*NH_ + (size_t)elem4*4);
        float m = sm[p], r = sr[p];
        v[p].x = (t.x-m)*r; v[p].y = (t.y-m)*r; v[p].z = (t.z-m)*r; v[p].w = (t.w-m)*r;
    }
    float4 tw4 = *(const float4*)(tw + (size_t)elem4*4);
    float4 tb4 = *(const float4*)(tb + (size_t)elem4*4);
    #pragma unroll
    for (int q = 0; q < P_; ++q) {
        float4 a = {0.f,0.f,0.f,0.f};
        #pragma unroll
        for (int p = 0; p < P_; ++p) {
            float c = scw[q*P_ + p];
            a.x += c*v[p].x; a.y += c*v[p].y; a.z += c*v[p].z; a.w += c*v[p].w;
        }
        float rb = srow[q], cbq = scb[q];
        float4 o;
        o.x = tw4.x*a.x + tb4.x*rb + cbq;
        o.y = tw4.y*a.y + tb4.y*rb + cbq;
        o.z = tw4.z*a.z + tb4.z*rb + cbq;
        o.w = tw4.w*a.w + tb4.w*rb + cbq;
        *(float4*)(h2 + base + (size_t)q*NH_ + (size_t)elem4*4) = o;
    }
}

extern "C" void kernel_launch(void* const* d_in, const int* in_sizes, int n_in,
                              void* d_out, int out_size, void* d_ws, size_t ws_size,
                              hipStream_t stream) {
    const float* x  = (const float*)d_in[0];
    const int*   ew = (const int*)d_in[1];
    const float* gw = (const float*)d_in[2];
    const float* gb = (const float*)d_in[3];
    const float* tw = (const float*)d_in[4];
    const float* tb = (const float*)d_in[5];
    const float* cw = (const float*)d_in[6];
    const float* cb = (const float*)d_in[7];
    float* out = (float*)d_out;
    float* wf  = (float*)d_ws;

    // ws layout (floats):
    // mean1[192]@0 rstd1[192]@192 mean2[192]@384 rstd2[192]@576
    // pA[192*8*2]@768  pC[192*64*2]@3840  rowPtr(int)[2052]@28416
    // csrSrc(int)[16384]@30468  csrW[16384]@46852  -> end 63236 floats (~247 KB)
    float* mean1  = wf + 0;
    float* rstd1  = wf + 192;
    float* mean2  = wf + 384;
    float* rstd2  = wf + 576;
    float* pA     = wf + 768;
    float* pC     = wf + 3840;
    int*   rowPtr = (int*)(wf + 28416);
    int*   csrSrc = (int*)(wf + 30468);
    float* csrW   = wf + 46852;

    k_stats_x<<<NG_*8, 256, 0, stream>>>(x, pA);
    k_finalize<<<NG_, 64, 0, stream>>>(pA, 8, mean1, rstd1);
    k_build_csr<<<1, 1024, 0, stream>>>(ew, rowPtr, csrSrc, csrW);
    k_gather<<<B_*64, 256, 0, stream>>>(x, gw, gb, mean1, rstd1,
                                        rowPtr, csrSrc, csrW, out, pC);
    k_finalize<<<NG_, 64, 0, stream>>>(pC, 64, mean2, rstd2);
    k_mix<<<B_*128, 256, 0, stream>>>(out, tw, tb, cw, cb, mean2, rstd2);
}

// Round 4
// 357.408 us; speedup vs baseline: 1.6915x; 1.0288x over previous
//
#include <hip/hip_runtime.h>

#define B_ 16
#define P_ 12
#define N_ 2048
#define H_ 64
#define E_ 16384
#define NH_ (N_*H_)            // 131072
#define NG_ (B_*P_)            // 192

// ---------------- fused: per-plane LN1 stats (blocks 0..191) + CSR build (block 192) ----
__global__ __launch_bounds__(1024) void k_stats_csr(const float* __restrict__ x,
                                                    const int* __restrict__ ew,
                                                    float* __restrict__ mean1,
                                                    float* __restrict__ rstd1,
                                                    int* __restrict__ rowPtr,
                                                    int* __restrict__ csrSrc,
                                                    float* __restrict__ csrW) {
    __shared__ int   sDeg[N_];
    __shared__ int   sA[N_];
    __shared__ int   sB[N_];
    __shared__ float sDinv[N_];
    __shared__ int   sFlag;
    __shared__ float ls[16], lq[16];
    int tid = threadIdx.x;
    if (blockIdx.x < NG_) {
        // ---- LN1 stats for one (b,p) plane ----
        int g = blockIdx.x;
        const float4* xg = (const float4*)(x + (size_t)g * NH_);
        float s = 0.f, q = 0.f;
        #pragma unroll 8
        for (int i = 0; i < 32; ++i) {
            float4 v = xg[i*1024 + tid];
            s += v.x + v.y + v.z + v.w;
            q += v.x*v.x + v.y*v.y + v.z*v.z + v.w*v.w;
        }
        for (int off = 32; off; off >>= 1) { s += __shfl_down(s, off); q += __shfl_down(q, off); }
        int wid = tid >> 6, lane = tid & 63;
        if (!lane) { ls[wid] = s; lq[wid] = q; }
        __syncthreads();
        if (!tid) {
            float S = 0.f, Q = 0.f;
            #pragma unroll
            for (int i = 0; i < 16; ++i) { S += ls[i]; Q += lq[i]; }
            float m = S * (1.0f/NH_);
            float v = Q * (1.0f/NH_) - m*m;
            mean1[g] = m;
            rstd1[g] = rsqrtf(v + 1e-5f);
        }
        return;
    }
    // ---- CSR build (single block) with int32/int64 detection ----
    if (!tid) sFlag = 1;
    for (int i = tid; i < N_; i += 1024) sDeg[i] = 0;
    __syncthreads();
    if (tid < 256) { if (ew[2*tid+1] != 0) atomicAnd(&sFlag, 0); }
    __syncthreads();
    int is64 = sFlag;
    for (int e = tid; e < E_; e += 1024) {
        int dst = is64 ? ew[2*(E_+e)] : ew[E_+e];
        atomicAdd(&sDeg[dst], 1);
    }
    __syncthreads();
    for (int i = tid; i < N_; i += 1024) {
        int d = sDeg[i];
        sDinv[i] = d > 0 ? rsqrtf((float)d) : 0.f;
        sA[i] = d;
    }
    __syncthreads();
    int* in = sA; int* out = sB;
    for (int st = 1; st < N_; st <<= 1) {
        for (int i = tid; i < N_; i += 1024) {
            int v = in[i];
            if (i >= st) v += in[i-st];
            out[i] = v;
        }
        __syncthreads();
        int* t = in; in = out; out = t;
    }
    for (int i = tid; i < N_; i += 1024) {
        int excl = in[i] - sDeg[i];
        rowPtr[i] = excl;
        out[i] = excl;
    }
    if (!tid) rowPtr[N_] = E_;
    __syncthreads();
    for (int e = tid; e < E_; e += 1024) {
        int src = is64 ? ew[2*e]       : ew[e];
        int dst = is64 ? ew[2*(E_+e)]  : ew[E_+e];
        int pos = atomicAdd(&out[dst], 1);
        csrSrc[pos] = src;
        csrW[pos] = sDinv[src] * sDinv[dst];
    }
}

// ---------------- finalize: partials -> mean/rstd per group (any cnt) ----------------
__global__ __launch_bounds__(64) void k_finalize(const float* __restrict__ partials, int cnt,
                                                 float* __restrict__ mean, float* __restrict__ rstd) {
    int g = blockIdx.x, lane = threadIdx.x;
    float s = 0.f, q = 0.f;
    for (int i = lane; i < cnt; i += 64) {
        s += partials[(g*cnt+i)*2];
        q += partials[(g*cnt+i)*2+1];
    }
    for (int off = 32; off; off >>= 1) { s += __shfl_down(s, off); q += __shfl_down(q, off); }
    if (!lane) {
        float m = s * (1.0f/NH_);
        float v = q * (1.0f/NH_) - m*m;
        mean[g] = m;
        rstd[g] = rsqrtf(v + 1e-5f);
    }
}

// ---------------- gather v3: per-wave 4 nodes, all 12 p-planes of one b ----
// h2[b,p,n,h] = rstd*acc_p - mean*rstd*Bn + An
__global__ __launch_bounds__(256) void k_gather(const float* __restrict__ x,
                                                const float* __restrict__ gw,
                                                const float* __restrict__ gb,
                                                const float* __restrict__ mean1,
                                                const float* __restrict__ rstd1,
                                                const int* __restrict__ rowPtr,
                                                const int* __restrict__ csrSrc,
                                                const float* __restrict__ csrW,
                                                float* __restrict__ h2,        // staged in d_out
                                                float* __restrict__ partials /*[192][128][2]*/) {
    int b     = blockIdx.x & 15;           // XCD = blockIdx%8 = b%8 -> b pinned per XCD
    int chunk = blockIdx.x >> 4;           // 0..127, 16 nodes each
    int wid = threadIdx.x >> 6, lane = threadIdx.x & 63;
    __shared__ float s_rs[P_], s_mrs[P_];
    __shared__ float red[4][P_][2];
    if (threadIdx.x < P_) {
        float m = mean1[b*P_ + threadIdx.x], r = rstd1[b*P_ + threadIdx.x];
        s_rs[threadIdx.x] = r; s_mrs[threadIdx.x] = m*r;
    }
    __syncthreads();
    const float* xb = x + (size_t)b * P_ * NH_;
    float sp[P_], qp[P_];
    #pragma unroll
    for (int p = 0; p < P_; ++p) { sp[p] = 0.f; qp[p] = 0.f; }
    #pragma unroll
    for (int i = 0; i < 4; ++i) {
        int n  = chunk*16 + wid*4 + i;
        int r0 = rowPtr[n], r1 = rowPtr[n+1];
        float acc[P_];
        #pragma unroll
        for (int p = 0; p < P_; ++p) acc[p] = 0.f;
        float An = 0.f, Bn = 0.f;
        if (r0 < r1) {
            int   src = csrSrc[r0];
            float w   = csrW[r0];
            for (int j = r0; j < r1; ++j) {
                int   ro  = src*H_ + lane;
                float gwv = gw[ro];
                float gbv = gb[ro];
                int   nsrc = 0; float nw = 0.f;
                if (j+1 < r1) { nsrc = csrSrc[j+1]; nw = csrW[j+1]; }  // prefetch
                float t = w * gwv;
                Bn += t;
                An += w * gbv;
                #pragma unroll
                for (int p = 0; p < P_; ++p)
                    acc[p] += t * xb[(size_t)p*NH_ + ro];
                src = nsrc; w = nw;
            }
        }
        size_t ob = (size_t)b*P_*NH_ + (size_t)n*H_ + lane;
        #pragma unroll
        for (int p = 0; p < P_; ++p) {
            float val = s_rs[p]*acc[p] - s_mrs[p]*Bn + An;
            h2[ob + (size_t)p*NH_] = val;
            sp[p] += val; qp[p] += val*val;
        }
    }
    #pragma unroll
    for (int p = 0; p < P_; ++p) {
        float s = sp[p], q = qp[p];
        for (int off = 32; off; off >>= 1) { s += __shfl_down(s, off); q += __shfl_down(q, off); }
        if (!lane) { red[wid][p][0] = s; red[wid][p][1] = q; }
    }
    __syncthreads();
    if (threadIdx.x < P_*2) {
        int p = threadIdx.x >> 1, c = threadIdx.x & 1;
        float v = red[0][p][c] + red[1][p][c] + red[2][p][c] + red[3][p][c];
        partials[(((b*P_ + p) << 7) + chunk)*2 + c] = v;
    }
}

// ---------------- mix: LN2 + 1x1 conv over P, in place on d_out ----------------
__global__ __launch_bounds__(256) void k_mix(float* __restrict__ h2,   // in/out = d_out
                                             const float* __restrict__ tw,
                                             const float* __restrict__ tb,
                                             const float* __restrict__ cw,
                                             const float* __restrict__ cb,
                                             const float* __restrict__ mean2,
                                             const float* __restrict__ rstd2) {
    __shared__ float scw[P_*P_], scb[P_], sm[P_], sr[P_], srow[P_];
    int b     = blockIdx.x >> 7;
    int chunk = blockIdx.x & 127;
    int tid   = threadIdx.x;
    if (tid < P_*P_) scw[tid] = cw[tid];
    if (tid < P_) {
        scb[tid] = cb[tid];
        sm[tid]  = mean2[b*P_ + tid];
        sr[tid]  = rstd2[b*P_ + tid];
    }
    __syncthreads();
    if (tid < P_) {
        float rs = 0.f;
        #pragma unroll
        for (int p = 0; p < P_; ++p) rs += scw[tid*P_ + p];
        srow[tid] = rs;
    }
    __syncthreads();
    int elem4 = chunk*256 + tid;           // 0..32767 = NH_/4
    size_t base = (size_t)b * P_ * NH_;
    float4 v[P_];
    #pragma unroll
    for (int p = 0; p < P_; ++p) {
        float4 t = *(const float4*)(h2 + base + (size_t)p*NH_ + (size_t)elem4*4);
        float m = sm[p], r = sr[p];
        v[p].x = (t.x-m)*r; v[p].y = (t.y-m)*r; v[p].z = (t.z-m)*r; v[p].w = (t.w-m)*r;
    }
    float4 tw4 = *(const float4*)(tw + (size_t)elem4*4);
    float4 tb4 = *(const float4*)(tb + (size_t)elem4*4);
    #pragma unroll
    for (int q = 0; q < P_; ++q) {
        float4 a = {0.f,0.f,0.f,0.f};
        #pragma unroll
        for (int p = 0; p < P_; ++p) {
            float c = scw[q*P_ + p];
            a.x += c*v[p].x; a.y += c*v[p].y; a.z += c*v[p].z; a.w += c*v[p].w;
        }
        float rb = srow[q], cbq = scb[q];
        float4 o;
        o.x = tw4.x*a.x + tb4.x*rb + cbq;
        o.y = tw4.y*a.y + tb4.y*rb + cbq;
        o.z = tw4.z*a.z + tb4.z*rb + cbq;
        o.w = tw4.w*a.w + tb4.w*rb + cbq;
        *(float4*)(h2 + base + (size_t)q*NH_ + (size_t)elem4*4) = o;
    }
}

extern "C" void kernel_launch(void* const* d_in, const int* in_sizes, int n_in,
                              void* d_out, int out_size, void* d_ws, size_t ws_size,
                              hipStream_t stream) {
    const float* x  = (const float*)d_in[0];
    const int*   ew = (const int*)d_in[1];
    const float* gw = (const float*)d_in[2];
    const float* gb = (const float*)d_in[3];
    const float* tw = (const float*)d_in[4];
    const float* tb = (const float*)d_in[5];
    const float* cw = (const float*)d_in[6];
    const float* cb = (const float*)d_in[7];
    float* out = (float*)d_out;
    float* wf  = (float*)d_ws;

    // ws layout (floats):
    // mean1[192]@0 rstd1[192]@192 mean2[192]@384 rstd2[192]@576
    // pC[192*128*2=49152]@768 -> end 49920
    // rowPtr(int)[2052]@49920 -> end 51972
    // csrSrc(int)[16384]@51972 -> 68356
    // csrW[16384]@68356 -> 84740 floats (~339 KB)
    float* mean1  = wf + 0;
    float* rstd1  = wf + 192;
    float* mean2  = wf + 384;
    float* rstd2  = wf + 576;
    float* pC     = wf + 768;
    int*   rowPtr = (int*)(wf + 49920);
    int*   csrSrc = (int*)(wf + 51972);
    float* csrW   = wf + 68356;

    k_stats_csr<<<NG_ + 1, 1024, 0, stream>>>(x, ew, mean1, rstd1, rowPtr, csrSrc, csrW);
    k_gather<<<B_*128, 256, 0, stream>>>(x, gw, gb, mean1, rstd1,
                                         rowPtr, csrSrc, csrW, out, pC);
    k_finalize<<<NG_, 64, 0, stream>>>(pC, 128, mean2, rstd2);
    k_mix<<<B_*128, 256, 0, stream>>>(out, tw, tb, cw, cb, mean2, rstd2);
}